// Round 10
// baseline (64.067 us; speedup 1.0000x reference)
//
#include <hip/hip_runtime.h>

#define TDIM 4096

// Per-role chain descriptors. flags: 1=NS diff, 2=EE diff, 4=RESET after.
// Roles: 0: joints 1-8 (chains A,B; reset after j4)
//        1: joints 9-13 (stem + 12,13)    — stem NS diffs counted here
//        2: joints 9,10,11 (no diff) + 14-17
//        3: joints 9,10,11 (no diff) + 18-21
typedef struct { int ik_ch, dq_ch, off3, flags; } Slot;

__device__ const Slot g_slots[4][8] = {
  { {  0,  8,  3, 1}, {  8, 16,  6, 1}, { 16, 24,  9, 1}, { 24, 32, 12, 6},
    { 32, 40, 15, 1}, { 40, 48, 18, 1}, { 48, 56, 21, 1}, { 56, 64, 24, 2} },
  { { 64, 72, 27, 1}, { 72, 80, 30, 1}, { 80, 88, 33, 1}, { 88, 96, 36, 1},
    { 96,104, 39, 2}, {  0,  0,  0, 0}, {  0,  0,  0, 0}, {  0,  0,  0, 0} },
  { { 64, 72, 27, 0}, { 72, 80, 30, 0}, { 80, 88, 33, 0}, {104,112, 42, 1},
    {112,120, 45, 1}, {120,128, 48, 1}, {128,136, 51, 2}, {  0,  0,  0, 0} },
  { { 64, 72, 27, 0}, { 72, 80, 30, 0}, { 80, 88, 33, 0}, {136,144, 54, 1},
    {144,152, 57, 1}, {152,160, 60, 1}, {160,168, 63, 2}, {  0,  0,  0, 0} },
};
__device__ const int g_nslots[4] = { 8, 5, 7, 7 };

// frame layout: f[0..8]=R (row major), f[9..11]=pos, f[12..15]=parent raw quat
__device__ __forceinline__ void fk_step(float* __restrict__ f,
                                        const float* __restrict__ q,
                                        float o0, float o1, float o2) {
  const float pw = f[12], px = f[13], py = f[14], pz = f[15];
  float lw = pw*q[0] + px*q[1] + py*q[2] + pz*q[3];
  float lx = pw*q[1] - px*q[0] - py*q[3] + pz*q[2];
  float ly = pw*q[2] + px*q[3] - py*q[0] - pz*q[1];
  float lz = pw*q[3] - px*q[2] + py*q[1] - pz*q[0];
  float n2 = lw*lw + lx*lx + ly*ly + lz*lz;
  float inv = rsqrtf(fmaxf(n2, 1e-16f));
  lw *= inv; lx *= inv; ly *= inv; lz *= inv;
  float xx = lx*lx, yy = ly*ly, zz = lz*lz;
  float xy = lx*ly, xz = lx*lz, yz = ly*lz;
  float wx = lw*lx, wy = lw*ly, wz = lw*lz;
  float m0 = 1.0f-2.0f*(yy+zz), m1 = 2.0f*(xy-wz),      m2 = 2.0f*(xz+wy);
  float m3 = 2.0f*(xy+wz),      m4 = 1.0f-2.0f*(xx+zz), m5 = 2.0f*(yz-wx);
  float m6 = 2.0f*(xz-wy),      m7 = 2.0f*(yz+wx),      m8 = 1.0f-2.0f*(xx+yy);
  f[9]  += f[0]*o0 + f[1]*o1 + f[2]*o2;
  f[10] += f[3]*o0 + f[4]*o1 + f[5]*o2;
  f[11] += f[6]*o0 + f[7]*o1 + f[8]*o2;
  float r0 = f[0]*m0 + f[1]*m3 + f[2]*m6;
  float r1 = f[0]*m1 + f[1]*m4 + f[2]*m7;
  float r2 = f[0]*m2 + f[1]*m5 + f[2]*m8;
  float r3 = f[3]*m0 + f[4]*m3 + f[5]*m6;
  float r4 = f[3]*m1 + f[4]*m4 + f[5]*m7;
  float r5 = f[3]*m2 + f[4]*m5 + f[5]*m8;
  float r6 = f[6]*m0 + f[7]*m3 + f[8]*m6;
  float r7 = f[6]*m1 + f[7]*m4 + f[8]*m7;
  float r8 = f[6]*m2 + f[7]*m5 + f[8]*m8;
  f[0]=r0; f[1]=r1; f[2]=r2; f[3]=r3; f[4]=r4; f[5]=r5; f[6]=r6; f[7]=r7; f[8]=r8;
  f[12]=q[0]; f[13]=q[1]; f[14]=q[2]; f[15]=q[3];
}

// 4 roles x 512 blocks; role = blockIdx & 3 (block-uniform, scalar table reads).
// Each thread runs its role's chain start-to-finish: no inter-thread coupling.
__global__ __launch_bounds__(256) void fk_loss_kernel(
    const float* __restrict__ ik,   // (32, 168, 4096)
    const float* __restrict__ dec,  // (32, 176, 4096)
    const float* __restrict__ tgt,  // (32, 176, 4096)
    const float* __restrict__ mean, // (176,)
    const float* __restrict__ stdv, // (176,)
    const float* __restrict__ offs, // (22, 3)
    float* __restrict__ out)
{
  __shared__ float s_mean[176];
  __shared__ float s_std[176];
  __shared__ float s_wsum[4];
  const int tid = threadIdx.x;
  for (int i = tid; i < 176; i += 256) { s_mean[i] = mean[i]; s_std[i] = stdv[i]; }
  __syncthreads();

  const int role = blockIdx.x & 3;
  const int idx  = (blockIdx.x >> 2) * 256 + tid;   // 0 .. 131071
  const int b = idx >> 12;
  const int t = idx & 4095;
  const float* __restrict__ pik  = ik  + (size_t)b * 168 * TDIM + t;
  const float* __restrict__ pdec = dec + (size_t)b * 176 * TDIM + t;
  const float* __restrict__ ptgt = tgt + (size_t)b * 176 * TDIM + t;

  // denormed tgt root quat (tgt has set_root=False)
  float rq[4];
  #pragma unroll
  for (int c = 0; c < 4; c++) rq[c] = fmaf(ptgt[c * TDIM], s_std[c], s_mean[c]);

  float see_p = 0.f, see_m = 0.f, srg_p = 0.f, srg_m = 0.f;
  float fik[16], fdec[16], ftgt[16];

#define RESET()                                                                \
  { _Pragma("unroll")                                                          \
    for (int c = 0; c < 16; c++) { fik[c] = 0.f; fdec[c] = 0.f; ftgt[c] = 0.f; } \
    fik[0]=fik[4]=fik[8]=1.f; fdec[0]=fdec[4]=fdec[8]=1.f; ftgt[0]=ftgt[4]=ftgt[8]=1.f; \
    fik[12]=1.f; fdec[12]=1.f;                                                 \
    ftgt[12]=rq[0]; ftgt[13]=rq[1]; ftgt[14]=rq[2]; ftgt[15]=rq[3]; }

  RESET();

  const int nslots = g_nslots[role];
  #pragma unroll 1
  for (int k = 0; k < nslots; ++k) {
    const int ikch  = g_slots[role][k].ik_ch;
    const int dqch  = g_slots[role][k].dq_ch;
    const int off3  = g_slots[role][k].off3;
    const int flags = g_slots[role][k].flags;

    float qi[4], qd[4], qt[4];
    #pragma unroll
    for (int c = 0; c < 4; c++) {
      qi[c] = pik [(size_t)(ikch + c) * TDIM];
      qd[c] = pdec[(size_t)(dqch + c) * TDIM];
      qt[c] = ptgt[(size_t)(dqch + c) * TDIM];
    }
    #pragma unroll
    for (int c = 0; c < 4; c++) {
      const float sd = s_std[dqch + c], mn = s_mean[dqch + c];
      qi[c] = fmaf(qi[c], sd, mn);
      qd[c] = fmaf(qd[c], sd, mn);
      qt[c] = fmaf(qt[c], sd, mn);
    }
    const float o0 = offs[off3], o1 = offs[off3 + 1], o2 = offs[off3 + 2];
    fk_step(fik,  qi, o0, o1, o2);
    fk_step(fdec, qd, o0, o1, o2);
    fk_step(ftgt, qt, o0, o1, o2);

    if (flags & 1) {   // non-sparse: dec vs ik
      #pragma unroll
      for (int c = 0; c < 3; c++) { float d = fdec[9+c] - fik[9+c]; srg_p = fmaf(d, d, srg_p); }
      #pragma unroll
      for (int c = 0; c < 9; c++) { float d = fdec[c]   - fik[c];   srg_m = fmaf(d, d, srg_m); }
    }
    if (flags & 2) {   // EE: ik vs tgt
      #pragma unroll
      for (int c = 0; c < 3; c++) { float d = fik[9+c] - ftgt[9+c]; see_p = fmaf(d, d, see_p); }
      #pragma unroll
      for (int c = 0; c < 9; c++) { float d = fik[c]   - ftgt[c];   see_m = fmaf(d, d, see_m); }
    }
    if (flags & 4) RESET();
  }

#undef RESET

  // weights: see_p/(BT*15) + see_m/(BT*45) + 0.1*(srg_p/(BT*48) + srg_m/(BT*144))
  const float W1 = 1.0f / 1966080.0f;
  const float W2 = 1.0f / 5898240.0f;
  const float W3 = 0.1f / 6291456.0f;
  const float W4 = 0.1f / 18874368.0f;
  float val = see_p * W1 + see_m * W2 + srg_p * W3 + srg_m * W4;

  #pragma unroll
  for (int o = 32; o > 0; o >>= 1) val += __shfl_down(val, o, 64);
  const int wid = tid >> 6;
  if ((tid & 63) == 0) s_wsum[wid] = val;
  __syncthreads();
  if (tid == 0) atomicAdd(out, s_wsum[0] + s_wsum[1] + s_wsum[2] + s_wsum[3]);
}

extern "C" void kernel_launch(void* const* d_in, const int* in_sizes, int n_in,
                              void* d_out, int out_size, void* d_ws, size_t ws_size,
                              hipStream_t stream) {
  const float* ik   = (const float*)d_in[1];
  const float* dec  = (const float*)d_in[2];
  const float* tgt  = (const float*)d_in[3];
  const float* mean = (const float*)d_in[4];
  const float* stdv = (const float*)d_in[5];
  const float* offs = (const float*)d_in[6];
  float* out = (float*)d_out;

  hipMemsetAsync(out, 0, sizeof(float), stream);
  // 4 roles x 512 (b,t)-blocks, interleaved so same-(b,t) roles share L2
  fk_loss_kernel<<<dim3(2048), dim3(256), 0, stream>>>(ik, dec, tgt, mean, stdv, offs, out);
}